// Round 1
// baseline (126.578 us; speedup 1.0000x reference)
//
#include <hip/hip_runtime.h>
#include <math.h>

#define E_TOTAL 32768
#define NUM_NODES 4096
#define SCALE 0.70710678118654752f

typedef __attribute__((ext_vector_type(8))) short bfrag;
typedef __attribute__((ext_vector_type(16))) float facc;

__device__ inline unsigned short f2bf(float f) {
  unsigned int u = __float_as_uint(f);
  unsigned int r = (u + 0x7FFFu + ((u >> 16) & 1u)) >> 16;
  return (unsigned short)r;
}
__device__ inline float bf2f(unsigned short s) {
  return __uint_as_float(((unsigned int)s) << 16);
}
__device__ inline void cvt8(const float* v, bfrag& hi, bfrag& lo) {
#pragma unroll
  for (int i = 0; i < 8; ++i) {
    unsigned short h = f2bf(v[i]);
    hi[i] = (short)h;
    lo[i] = (short)f2bf(v[i] - bf2f(h));
  }
}

// ---------------------------------------------------------------------------
// Combined prep: blocks 0..95 W_p frags, 96..102 W_q frags, 103..230 offsets
// frag layout per n-tile nt=c*6+w: [ks(4)][hl(2)][lane(64)][j(8)] bf16 (8 KB)
//   element = W_p[d][w*512 + c*32 + (lane&31)], d = ks*16 + (lane>>5)*8 + j
// ---------------------------------------------------------------------------
__global__ __launch_bounds__(256) void prep_kernel(
    const float* __restrict__ Wp, const float* __restrict__ Wq,
    const int* __restrict__ index,
    unsigned short* __restrict__ fragWp, unsigned short* __restrict__ fragWq,
    int* __restrict__ offs)
{
  const int b = blockIdx.x, t = threadIdx.x;
  if (b < 96) {
    __shared__ unsigned short lds[4096];
    const int c = b / 6, w = b - c * 6;
    const int colbase = w * 512 + c * 32;
    const int cl = t & 31, dg = t >> 5;
#pragma unroll
    for (int i = 0; i < 8; ++i) {
      const int d = dg * 8 + i;
      const float v = Wp[(size_t)d * 3072 + colbase + cl];
      const unsigned short hi = f2bf(v);
      const unsigned short lo = f2bf(v - bf2f(hi));
      const int ks = d >> 4;
      const int lane = ((d >> 3) & 1) * 32 + cl;
      const int j = d & 7;
      lds[(ks * 2 + 0) * 512 + lane * 8 + j] = hi;
      lds[(ks * 2 + 1) * 512 + lane * 8 + j] = lo;
    }
    __syncthreads();
    unsigned short* dst = fragWp + (size_t)b * 4096;
    ((uint4*)dst)[t] = ((const uint4*)lds)[t];
    ((uint4*)dst)[t + 256] = ((const uint4*)lds)[t + 256];
  } else if (b < 103) {
    const int slot = b - 96;
    const int w = (slot == 6) ? 5 : slot;
    const float sgn = (slot == 6) ? -1.f : 1.f;
    for (int tt = t; tt < 512; tt += 256) {
      const int lane = tt >> 3, j = tt & 7;
      const int o = lane & 31, c = (lane >> 5) * 8 + j;
      const float v = sgn * Wq[(size_t)(w * 16 + c) * 32 + o];
      const unsigned short hi = f2bf(v);
      const unsigned short lo = f2bf(v - bf2f(hi));
      fragWq[slot * 1024 + lane * 8 + j] = hi;
      fragWq[slot * 1024 + 512 + lane * 8 + j] = lo;
    }
  } else {
    const int tg = (b - 103) * 256 + t;
    if (tg >= E_TOTAL) return;
    const int cur = index[tg];
    const int prev = (tg == 0) ? -1 : index[tg - 1];
    for (int n = prev + 1; n <= cur; ++n) offs[n] = tg;
    if (tg == E_TOTAL - 1)
      for (int n = cur + 1; n <= NUM_NODES; ++n) offs[n] = E_TOTAL;
  }
}

// ---------------------------------------------------------------------------
// Main: 4 waves/block, 32 edges/block, 1024 blocks (4 blocks/CU -> 16 w/CU).
// Each wave owns a contiguous c-quarter of the 96 W_p tiles (24 tiles, all 6
// w per c) for the SAME 32 edges; partial z reduced across waves in LDS.
// A-frags loaded DIRECTLY global->VGPR (L2-resident, coalesced 1 KB/inst),
// register ping-pong prefetch, ZERO barriers in the K-loop.
// hi/lo precision: cc0 = Ah*Bh chain; cc12 = Ah*Bl + Al*Bh merged chain
// (MFMA does the add for free vs the old 3-chain + VALU-add form).
// ---------------------------------------------------------------------------
__global__ __launch_bounds__(256, 2) void main_kernel(
    const float* __restrict__ x_q, const float* __restrict__ x_k,
    const float* __restrict__ emb,
    const unsigned short* __restrict__ fragWp,
    const unsigned short* __restrict__ fragWq,
    float* __restrict__ z)
{
  __shared__ float xk_t[64][33];   // 8.25 KB, padded
  __shared__ float zred[4][32][4]; // 2 KB

  const int t = threadIdx.x;
  const int lane = t & 63, wv = t >> 6;
  const int col = lane & 31, half = lane >> 5;
  const int eb = blockIdx.x * 32;
  const int e = eb + col;

  // stage x_k transposed: thread t -> edge t>>3, d-offset (t&7)*8
  {
    const int er = t >> 3, dq = (t & 7) * 8;
    const float* src = x_k + (size_t)(eb + er) * 64 + dq;
#pragma unroll
    for (int i = 0; i < 2; ++i) {
      float4 v = *(const float4*)(src + i * 4);
      xk_t[dq + i * 4 + 0][er] = v.x;
      xk_t[dq + i * 4 + 1][er] = v.y;
      xk_t[dq + i * 4 + 2][er] = v.z;
      xk_t[dq + i * 4 + 3][er] = v.w;
    }
  }

  // emb B-fragments hi/lo: B[k=d][col=e], d = ks*16 + half*8 + j
  bfrag ebh[4], ebl[4];
#pragma unroll
  for (int ks = 0; ks < 4; ++ks) {
    float tmp[8];
    *(float4*)&tmp[0] = *(const float4*)(emb + (size_t)e * 64 + ks * 16 + half * 8);
    *(float4*)&tmp[4] = *(const float4*)(emb + (size_t)e * 64 + ks * 16 + half * 8 + 4);
    cvt8(tmp, ebh[ks], ebl[ks]);
  }

  facc ka0 = {0}, ka1 = {0}, ka2 = {0}, ka3 = {0};

  // per-wave A stream: contiguous c-quarter, tile it at fbase + it*4096 shorts
  // (global tile nt = wv*24 + it = c*6 + w, c = wv*4 + it/6, w = it%6)
  const unsigned short* fbase = fragWp + (size_t)wv * 24 * 4096 + lane * 8;

  bfrag curh[4], curl[4], nxth[4], nxtl[4];
#pragma unroll
  for (int ks = 0; ks < 4; ++ks) {
    *(uint4*)&curh[ks] = *(const uint4*)(fbase + ks * 1024);
    *(uint4*)&curl[ks] = *(const uint4*)(fbase + ks * 1024 + 512);
  }

  __syncthreads();  // xk_t ready (only barrier before the end)

  float xkc0 = 0.f, xkc1 = 0.f, xkc2 = 0.f, xkc3 = 0.f;

#pragma unroll 6
  for (int it = 0; it < 24; ++it) {
    const int j = it % 6;          // static under unroll-6
    // prefetch next tile's 8 frags into the other register set
    {
      const int itn = (it < 23) ? it + 1 : 23;
      const unsigned short* gp = fbase + (size_t)itn * 4096;
#pragma unroll
      for (int ks = 0; ks < 4; ++ks) {
        *(uint4*)&nxth[ks] = *(const uint4*)(gp + ks * 1024);
        *(uint4*)&nxtl[ks] = *(const uint4*)(gp + ks * 1024 + 512);
      }
    }
    if (j == 0) {
      const int c16 = (wv << 2) + it / 6;
      xkc0 = xk_t[c16][col];
      xkc1 = xk_t[16 + c16][col];
      xkc2 = xk_t[32 + c16][col];
      xkc3 = xk_t[48 + c16][col];
    }
    facc cc0 = {0.f}, cc12 = {0.f};  // hi*hi chain; merged hi*lo+lo*hi chain
#pragma unroll
    for (int ks = 0; ks < 4; ++ks) {
      cc0  = __builtin_amdgcn_mfma_f32_32x32x16_bf16(curh[ks], ebh[ks], cc0, 0, 0, 0);
      cc12 = __builtin_amdgcn_mfma_f32_32x32x16_bf16(curh[ks], ebl[ks], cc12, 0, 0, 0);
      cc12 = __builtin_amdgcn_mfma_f32_32x32x16_bf16(curl[ks], ebh[ks], cc12, 0, 0, 0);
    }
    // so2 contraction per w = j:
    //   w0: x0->m0  w1: x0->m2  w2: x2->m0  w3: x2->m2
    //   w4: x1->m1, x3->m3      w5: x3->m1, -x1->m3
    if (j < 4) {
      const float xv = (j & 2) ? xkc2 : xkc0;
      facc& kd = (j & 1) ? ka2 : ka0;
#pragma unroll
      for (int r = 0; r < 16; ++r)
        kd[r] = fmaf(xv, cc0[r] + cc12[r], kd[r]);
    } else if (j == 4) {
#pragma unroll
      for (int r = 0; r < 16; ++r) {
        const float s = cc0[r] + cc12[r];
        ka1[r] = fmaf(xkc1, s, ka1[r]);
        ka3[r] = fmaf(xkc3, s, ka3[r]);
      }
    } else {
#pragma unroll
      for (int r = 0; r < 16; ++r) {
        const float s = cc0[r] + cc12[r];
        ka1[r] = fmaf(xkc3, s, ka1[r]);
        ka3[r] = fmaf(-xkc1, s, ka3[r]);
      }
    }
    // rotate prefetch registers (coalesced away by regalloc under unroll)
#pragma unroll
    for (int ks = 0; ks < 4; ++ks) { curh[ks] = nxth[ks]; curl[ks] = nxtl[ks]; }
  }

  // ---- q via MFMA (same C layout as ka), partial z, cross-wave reduce
  bfrag xqh[4], xql[4];
#pragma unroll
  for (int a = 0; a < 4; ++a) {
    float tmp[8];
    *(float4*)&tmp[0] = *(const float4*)(x_q + (size_t)e * 64 + a * 16 + half * 8);
    *(float4*)&tmp[4] = *(const float4*)(x_q + (size_t)e * 64 + a * 16 + half * 8 + 4);
    cvt8(tmp, xqh[a], xql[a]);
  }
  float zp0 = 0.f, zp1 = 0.f, zp2 = 0.f, zp3 = 0.f;
  const int QA1[4] = {0, 1, 0, 3}, QS1[4] = {0, 4, 1, 4};
  const int QA2[4] = {2, 3, 2, 1}, QS2[4] = {2, 5, 3, 6};  // slot 6 = -Wq[5]
#pragma unroll
  for (int m = 0; m < 4; ++m) {
    facc qa = {0.f};
#pragma unroll
    for (int tm = 0; tm < 2; ++tm) {
      const int a = tm ? QA2[m] : QA1[m];
      const int sl = tm ? QS2[m] : QS1[m];
      bfrag wh, wl;
      *(uint4*)&wh = *(const uint4*)(fragWq + sl * 1024 + lane * 8);
      *(uint4*)&wl = *(const uint4*)(fragWq + sl * 1024 + 512 + lane * 8);
      qa = __builtin_amdgcn_mfma_f32_32x32x16_bf16(wh, xqh[a], qa, 0, 0, 0);
      qa = __builtin_amdgcn_mfma_f32_32x32x16_bf16(wh, xql[a], qa, 0, 0, 0);
      qa = __builtin_amdgcn_mfma_f32_32x32x16_bf16(wl, xqh[a], qa, 0, 0, 0);
    }
    const facc& km = (m == 0) ? ka0 : (m == 1) ? ka1 : (m == 2) ? ka2 : ka3;
#pragma unroll
    for (int r = 0; r < 16; ++r) {
      const float v = qa[r] * km[r];
      if (r < 4) zp0 += v;
      else if (r < 8) zp1 += v;
      else if (r < 12) zp2 += v;
      else zp3 += v;
    }
  }
  zp0 += __shfl_xor(zp0, 32);
  zp1 += __shfl_xor(zp1, 32);
  zp2 += __shfl_xor(zp2, 32);
  zp3 += __shfl_xor(zp3, 32);
  if (half == 0) {
    float4 v = {zp0, zp1, zp2, zp3};
    *(float4*)&zred[wv][col][0] = v;
  }
  __syncthreads();
  if (wv == 0 && half == 0) {
    float4 a0 = *(const float4*)&zred[0][col][0];
    float4 a1 = *(const float4*)&zred[1][col][0];
    float4 a2 = *(const float4*)&zred[2][col][0];
    float4 a3 = *(const float4*)&zred[3][col][0];
    float4 o = {(a0.x + a1.x + a2.x + a3.x) * SCALE,
                (a0.y + a1.y + a2.y + a3.y) * SCALE,
                (a0.z + a1.z + a2.z + a3.z) * SCALE,
                (a0.w + a1.w + a2.w + a3.w) * SCALE};
    *(float4*)&z[(size_t)e * 4] = o;
  }
}

// ---------------------------------------------------------------------------
__global__ __launch_bounds__(256) void softmax_kernel(
    const float* __restrict__ z, const int* __restrict__ offs,
    float* __restrict__ out)
{
  const int node = blockIdx.x * 4 + (threadIdx.x >> 6);
  const int lane = threadIdx.x & 63;
  const int start = offs[node], end = offs[node + 1];
  if (start >= end) return;
  const int h = lane & 3, eo = lane >> 2;
  float m = -INFINITY;
  for (int e = start + eo; e < end; e += 16) m = fmaxf(m, z[(size_t)e * 4 + h]);
#pragma unroll
  for (int s = 4; s < 64; s <<= 1) m = fmaxf(m, __shfl_xor(m, s));
  float sum = 0.f;
  for (int e = start + eo; e < end; e += 16) sum += __expf(z[(size_t)e * 4 + h] - m);
#pragma unroll
  for (int s = 4; s < 64; s <<= 1) sum += __shfl_xor(sum, s);
  const float inv = 1.f / sum;
  for (int e = start + eo; e < end; e += 16)
    out[(size_t)e * 4 + h] = __expf(z[(size_t)e * 4 + h] - m) * inv;
}

extern "C" void kernel_launch(void* const* d_in, const int* in_sizes, int n_in,
                              void* d_out, int out_size, void* d_ws, size_t ws_size,
                              hipStream_t stream) {
  const float* x_q = (const float*)d_in[0];
  const float* x_k = (const float*)d_in[1];
  const float* emb = (const float*)d_in[2];
  const int* index = (const int*)d_in[3];
  const float* W_q = (const float*)d_in[4];
  const float* W_p = (const float*)d_in[5];
  float* out = (float*)d_out;

  char* ws = (char*)d_ws;
  float* z = (float*)ws;                                                    // 524288 B
  int* offs = (int*)(ws + 524288);                                          // 16388 B (pad 32 KB)
  unsigned short* fragWp = (unsigned short*)(ws + 524288 + 32768);          // 786432 B
  unsigned short* fragWq = (unsigned short*)(ws + 524288 + 32768 + 786432); // 14336 B

  prep_kernel<<<231, 256, 0, stream>>>(W_p, W_q, index, fragWp, fragWq, offs);
  main_kernel<<<1024, 256, 0, stream>>>(x_q, x_k, emb, fragWp, fragWq, z);
  softmax_kernel<<<1024, 256, 0, stream>>>(z, offs, out);
}

// Round 2
// 124.731 us; speedup vs baseline: 1.0148x; 1.0148x over previous
//
#include <hip/hip_runtime.h>
#include <math.h>

#define E_TOTAL 32768
#define NUM_NODES 4096
#define SCALE 0.70710678118654752f

typedef __attribute__((ext_vector_type(8))) short bfrag;
typedef __attribute__((ext_vector_type(16))) float facc;

__device__ inline unsigned short f2bf(float f) {
  unsigned int u = __float_as_uint(f);
  unsigned int r = (u + 0x7FFFu + ((u >> 16) & 1u)) >> 16;
  return (unsigned short)r;
}
__device__ inline float bf2f(unsigned short s) {
  return __uint_as_float(((unsigned int)s) << 16);
}
__device__ inline void cvt8(const float* v, bfrag& hi, bfrag& lo) {
#pragma unroll
  for (int i = 0; i < 8; ++i) {
    unsigned short h = f2bf(v[i]);
    hi[i] = (short)h;
    lo[i] = (short)f2bf(v[i] - bf2f(h));
  }
}

// ---------------------------------------------------------------------------
// Combined prep: blocks 0..95 W_p frags, 96..102 W_q frags, 103..230 offsets
// frag layout per n-tile nt=c*6+w: [ks(4)][hl(2)][lane(64)][j(8)] bf16 (8 KB)
//   element = W_p[d][w*512 + c*32 + (lane&31)], d = ks*16 + (lane>>5)*8 + j
// ---------------------------------------------------------------------------
__global__ __launch_bounds__(256) void prep_kernel(
    const float* __restrict__ Wp, const float* __restrict__ Wq,
    const int* __restrict__ index,
    unsigned short* __restrict__ fragWp, unsigned short* __restrict__ fragWq,
    int* __restrict__ offs)
{
  const int b = blockIdx.x, t = threadIdx.x;
  if (b < 96) {
    __shared__ unsigned short lds[4096];
    const int c = b / 6, w = b - c * 6;
    const int colbase = w * 512 + c * 32;
    const int cl = t & 31, dg = t >> 5;
#pragma unroll
    for (int i = 0; i < 8; ++i) {
      const int d = dg * 8 + i;
      const float v = Wp[(size_t)d * 3072 + colbase + cl];
      const unsigned short hi = f2bf(v);
      const unsigned short lo = f2bf(v - bf2f(hi));
      const int ks = d >> 4;
      const int lane = ((d >> 3) & 1) * 32 + cl;
      const int j = d & 7;
      lds[(ks * 2 + 0) * 512 + lane * 8 + j] = hi;
      lds[(ks * 2 + 1) * 512 + lane * 8 + j] = lo;
    }
    __syncthreads();
    unsigned short* dst = fragWp + (size_t)b * 4096;
    ((uint4*)dst)[t] = ((const uint4*)lds)[t];
    ((uint4*)dst)[t + 256] = ((const uint4*)lds)[t + 256];
  } else if (b < 103) {
    const int slot = b - 96;
    const int w = (slot == 6) ? 5 : slot;
    const float sgn = (slot == 6) ? -1.f : 1.f;
    for (int tt = t; tt < 512; tt += 256) {
      const int lane = tt >> 3, j = tt & 7;
      const int o = lane & 31, c = (lane >> 5) * 8 + j;
      const float v = sgn * Wq[(size_t)(w * 16 + c) * 32 + o];
      const unsigned short hi = f2bf(v);
      const unsigned short lo = f2bf(v - bf2f(hi));
      fragWq[slot * 1024 + lane * 8 + j] = hi;
      fragWq[slot * 1024 + 512 + lane * 8 + j] = lo;
    }
  } else {
    const int tg = (b - 103) * 256 + t;
    if (tg >= E_TOTAL) return;
    const int cur = index[tg];
    const int prev = (tg == 0) ? -1 : index[tg - 1];
    for (int n = prev + 1; n <= cur; ++n) offs[n] = tg;
    if (tg == E_TOTAL - 1)
      for (int n = cur + 1; n <= NUM_NODES; ++n) offs[n] = E_TOTAL;
  }
}

// ---------------------------------------------------------------------------
// Main: 256 blocks (1/CU), 4 waves/block, 128 edges/block, 32 edges/wave.
// ALL 4 waves stream the SAME 96 W_p tiles in the same order -> wave 0's L2
// miss fills L1 (32 KB = 4-tile window), waves 1-3 hit L1: per-CU L2 pull
// drops 4x (3 MB -> 768 KB). Drift self-corrects (laggards hit L1, leaders
// miss); a barrier every 24 tiles bounds it. Each wave's ka is COMPLETE
// (all 96 tiles) -> no cross-wave reduce, zero epilogue duplication.
// 3 independent MFMA chains of 4 (ILP for 1 wave/SIMD).
// ---------------------------------------------------------------------------
__global__ __launch_bounds__(256, 1) void main_kernel(
    const float* __restrict__ x_q, const float* __restrict__ x_k,
    const float* __restrict__ emb,
    const unsigned short* __restrict__ fragWp,
    const unsigned short* __restrict__ fragWq,
    float* __restrict__ z)
{
  __shared__ float xk_t[64][129];  // 33 KB, padded

  const int t = threadIdx.x;
  const int lane = t & 63, wv = t >> 6;
  const int col = lane & 31, half = lane >> 5;
  const int eb = blockIdx.x * 128;
  const int el = wv * 32 + col;
  const int e = eb + el;

  // stage x_k transposed: thread t -> edge t&127, d-half (t>>7)*32
  {
    const int er = t & 127, dh = (t >> 7) * 32;
    const float* src = x_k + (size_t)(eb + er) * 64 + dh;
#pragma unroll
    for (int i = 0; i < 8; ++i) {
      float4 v = *(const float4*)(src + i * 4);
      xk_t[dh + i * 4 + 0][er] = v.x;
      xk_t[dh + i * 4 + 1][er] = v.y;
      xk_t[dh + i * 4 + 2][er] = v.z;
      xk_t[dh + i * 4 + 3][er] = v.w;
    }
  }

  // emb B-fragments hi/lo for this wave's 32 edges: B[k=d][col=e]
  bfrag ebh[4], ebl[4];
#pragma unroll
  for (int ks = 0; ks < 4; ++ks) {
    float tmp[8];
    *(float4*)&tmp[0] = *(const float4*)(emb + (size_t)e * 64 + ks * 16 + half * 8);
    *(float4*)&tmp[4] = *(const float4*)(emb + (size_t)e * 64 + ks * 16 + half * 8 + 4);
    cvt8(tmp, ebh[ks], ebl[ks]);
  }

  facc ka0 = {0}, ka1 = {0}, ka2 = {0}, ka3 = {0};

  // A stream: ALL tiles, shared across waves. tile it at fbase + it*4096
  const unsigned short* fbase = fragWp + lane * 8;

  bfrag curh[4], curl[4], nxth[4], nxtl[4];
#pragma unroll
  for (int ks = 0; ks < 4; ++ks) {
    *(uint4*)&curh[ks] = *(const uint4*)(fbase + ks * 1024);
    *(uint4*)&curl[ks] = *(const uint4*)(fbase + ks * 1024 + 512);
  }

  __syncthreads();  // xk_t ready

  float xkc0 = 0.f, xkc1 = 0.f, xkc2 = 0.f, xkc3 = 0.f;

  for (int ot = 0; ot < 4; ++ot) {
#pragma unroll 6
    for (int ii = 0; ii < 24; ++ii) {
      const int it = ot * 24 + ii;
      const int j = ii % 6;        // static under unroll-6
      // prefetch next tile into the other register set
      {
        const int itn = (it < 95) ? it + 1 : 95;
        const unsigned short* gp = fbase + (size_t)itn * 4096;
#pragma unroll
        for (int ks = 0; ks < 4; ++ks) {
          *(uint4*)&nxth[ks] = *(const uint4*)(gp + ks * 1024);
          *(uint4*)&nxtl[ks] = *(const uint4*)(gp + ks * 1024 + 512);
        }
      }
      if (j == 0) {
        const int c16 = it / 6;
        xkc0 = xk_t[c16][el];
        xkc1 = xk_t[16 + c16][el];
        xkc2 = xk_t[32 + c16][el];
        xkc3 = xk_t[48 + c16][el];
      }
      facc cc0 = {0.f}, cc1 = {0.f}, cc2 = {0.f};  // 3 chains of 4 (ILP)
#pragma unroll
      for (int ks = 0; ks < 4; ++ks) {
        cc0 = __builtin_amdgcn_mfma_f32_32x32x16_bf16(curh[ks], ebh[ks], cc0, 0, 0, 0);
        cc1 = __builtin_amdgcn_mfma_f32_32x32x16_bf16(curh[ks], ebl[ks], cc1, 0, 0, 0);
        cc2 = __builtin_amdgcn_mfma_f32_32x32x16_bf16(curl[ks], ebh[ks], cc2, 0, 0, 0);
      }
      // so2 contraction per w = j:
      //   w0: x0->m0  w1: x0->m2  w2: x2->m0  w3: x2->m2
      //   w4: x1->m1, x3->m3      w5: x3->m1, -x1->m3
      if (j < 4) {
        const float xv = (j & 2) ? xkc2 : xkc0;
        facc& kd = (j & 1) ? ka2 : ka0;
#pragma unroll
        for (int r = 0; r < 16; ++r)
          kd[r] = fmaf(xv, cc0[r] + cc1[r] + cc2[r], kd[r]);
      } else if (j == 4) {
#pragma unroll
        for (int r = 0; r < 16; ++r) {
          const float s = cc0[r] + cc1[r] + cc2[r];
          ka1[r] = fmaf(xkc1, s, ka1[r]);
          ka3[r] = fmaf(xkc3, s, ka3[r]);
        }
      } else {
#pragma unroll
        for (int r = 0; r < 16; ++r) {
          const float s = cc0[r] + cc1[r] + cc2[r];
          ka1[r] = fmaf(xkc3, s, ka1[r]);
          ka3[r] = fmaf(-xkc1, s, ka3[r]);
        }
      }
      // rotate prefetch registers
#pragma unroll
      for (int ks = 0; ks < 4; ++ks) { curh[ks] = nxth[ks]; curl[ks] = nxtl[ks]; }
    }
    __syncthreads();  // re-sync waves every 24 tiles (bounds L1-stream drift)
  }

  // ---- q via MFMA (same C layout as ka), full z per wave, direct store
  bfrag xqh[4], xql[4];
#pragma unroll
  for (int a = 0; a < 4; ++a) {
    float tmp[8];
    *(float4*)&tmp[0] = *(const float4*)(x_q + (size_t)e * 64 + a * 16 + half * 8);
    *(float4*)&tmp[4] = *(const float4*)(x_q + (size_t)e * 64 + a * 16 + half * 8 + 4);
    cvt8(tmp, xqh[a], xql[a]);
  }
  float zp0 = 0.f, zp1 = 0.f, zp2 = 0.f, zp3 = 0.f;
  const int QA1[4] = {0, 1, 0, 3}, QS1[4] = {0, 4, 1, 4};
  const int QA2[4] = {2, 3, 2, 1}, QS2[4] = {2, 5, 3, 6};  // slot 6 = -Wq[5]
#pragma unroll
  for (int m = 0; m < 4; ++m) {
    facc qa = {0.f};
#pragma unroll
    for (int tm = 0; tm < 2; ++tm) {
      const int a = tm ? QA2[m] : QA1[m];
      const int sl = tm ? QS2[m] : QS1[m];
      bfrag wh, wl;
      *(uint4*)&wh = *(const uint4*)(fragWq + sl * 1024 + lane * 8);
      *(uint4*)&wl = *(const uint4*)(fragWq + sl * 1024 + 512 + lane * 8);
      qa = __builtin_amdgcn_mfma_f32_32x32x16_bf16(wh, xqh[a], qa, 0, 0, 0);
      qa = __builtin_amdgcn_mfma_f32_32x32x16_bf16(wh, xql[a], qa, 0, 0, 0);
      qa = __builtin_amdgcn_mfma_f32_32x32x16_bf16(wl, xqh[a], qa, 0, 0, 0);
    }
    const facc& km = (m == 0) ? ka0 : (m == 1) ? ka1 : (m == 2) ? ka2 : ka3;
#pragma unroll
    for (int r = 0; r < 16; ++r) {
      const float v = qa[r] * km[r];
      if (r < 4) zp0 += v;
      else if (r < 8) zp1 += v;
      else if (r < 12) zp2 += v;
      else zp3 += v;
    }
  }
  zp0 += __shfl_xor(zp0, 32);
  zp1 += __shfl_xor(zp1, 32);
  zp2 += __shfl_xor(zp2, 32);
  zp3 += __shfl_xor(zp3, 32);
  if (half == 0) {
    float4 v = {zp0 * SCALE, zp1 * SCALE, zp2 * SCALE, zp3 * SCALE};
    *(float4*)&z[(size_t)e * 4] = v;
  }
}

// ---------------------------------------------------------------------------
__global__ __launch_bounds__(256) void softmax_kernel(
    const float* __restrict__ z, const int* __restrict__ offs,
    float* __restrict__ out)
{
  const int node = blockIdx.x * 4 + (threadIdx.x >> 6);
  const int lane = threadIdx.x & 63;
  const int start = offs[node], end = offs[node + 1];
  if (start >= end) return;
  const int h = lane & 3, eo = lane >> 2;
  float m = -INFINITY;
  for (int e = start + eo; e < end; e += 16) m = fmaxf(m, z[(size_t)e * 4 + h]);
#pragma unroll
  for (int s = 4; s < 64; s <<= 1) m = fmaxf(m, __shfl_xor(m, s));
  float sum = 0.f;
  for (int e = start + eo; e < end; e += 16) sum += __expf(z[(size_t)e * 4 + h] - m);
#pragma unroll
  for (int s = 4; s < 64; s <<= 1) sum += __shfl_xor(sum, s);
  const float inv = 1.f / sum;
  for (int e = start + eo; e < end; e += 16)
    out[(size_t)e * 4 + h] = __expf(z[(size_t)e * 4 + h] - m) * inv;
}

extern "C" void kernel_launch(void* const* d_in, const int* in_sizes, int n_in,
                              void* d_out, int out_size, void* d_ws, size_t ws_size,
                              hipStream_t stream) {
  const float* x_q = (const float*)d_in[0];
  const float* x_k = (const float*)d_in[1];
  const float* emb = (const float*)d_in[2];
  const int* index = (const int*)d_in[3];
  const float* W_q = (const float*)d_in[4];
  const float* W_p = (const float*)d_in[5];
  float* out = (float*)d_out;

  char* ws = (char*)d_ws;
  float* z = (float*)ws;                                                    // 524288 B
  int* offs = (int*)(ws + 524288);                                          // 16388 B (pad 32 KB)
  unsigned short* fragWp = (unsigned short*)(ws + 524288 + 32768);          // 786432 B
  unsigned short* fragWq = (unsigned short*)(ws + 524288 + 32768 + 786432); // 14336 B

  prep_kernel<<<231, 256, 0, stream>>>(W_p, W_q, index, fragWp, fragWq, offs);
  main_kernel<<<256, 256, 0, stream>>>(x_q, x_k, emb, fragWp, fragWq, z);
  softmax_kernel<<<1024, 256, 0, stream>>>(z, offs, out);
}